// Round 5
// baseline (157.230 us; speedup 1.0000x reference)
//
#include <hip/hip_runtime.h>

#define D     2048
#define NEXP  4
#define BLK   256
#define NWAVE 4
#define EPSV  1e-5f

// ---- weight transpose: Wt[c][d], c: 0-3 Wb, 4-7 Wm, 8-23 Wr(i*4+j) ----
__global__ __launch_bounds__(256) void wt_kernel(
    const float* __restrict__ Wb, const float* __restrict__ Wm,
    const float* __restrict__ Wr, float* __restrict__ Wt)
{
    int idx = blockIdx.x * 256 + threadIdx.x;      // 24*2048 = 49152 = 192*256
    int c = idx / D;
    int d = idx % D;
    float v;
    if (c < 4)       v = Wb[d * 4 + c];
    else if (c < 8)  v = Wm[d * 4 + (c - 4)];
    else             v = Wr[d * 16 + (c - 8)];
    Wt[c * D + d] = v;
}

__global__ __launch_bounds__(BLK) void hc_kernel(
    const float* __restrict__ lo,      // [tok, D]
    const float* __restrict__ hs,      // [tok, NEXP, D]
    const float* __restrict__ Bm,      // [1, NEXP]
    const float* __restrict__ Am,      // [NEXP, 1]
    const float* __restrict__ Ar,      // [NEXP, NEXP]
    const float* __restrict__ s_alpha, // [NEXP, NEXP]
    const float* __restrict__ s_beta,  // [1, NEXP]
    const float* __restrict__ Wt,      // [24, D] transposed weights
    float* __restrict__ out)           // [tok, NEXP, D]
{
    __shared__ float hb_lds[D];        // 8 KB: H_bar (f32)
    __shared__ float red[NWAVE][2 * NEXP];
    __shared__ float stats[2][NEXP];
    __shared__ float coef[24];

    const int tid  = threadIdx.x;
    const int wave = tid >> 6;
    const int lane = tid & 63;
    const long tok = blockIdx.x;

    const float4* hs4  = (const float4*)(hs + tok * (long)(NEXP * D));
    const float4* lo4  = (const float4*)(lo + tok * (long)D);
    float4*       out4 = (float4*)(out + tok * (long)(NEXP * D));

    // ---- Phase 1: hidden rows -> REGISTERS (lane-contiguous f32x4), stats ----
    float4 h[NEXP][2];
    float sum[NEXP], sq[NEXP];
    #pragma unroll
    for (int n = 0; n < NEXP; ++n) { sum[n] = 0.f; sq[n] = 0.f; }

    #pragma unroll
    for (int n = 0; n < NEXP; ++n) {
        #pragma unroll
        for (int k = 0; k < 2; ++k) {
            float4 v = hs4[n * (D / 4) + tid + BLK * k];
            h[n][k] = v;
            sum[n] += v.x + v.y + v.z + v.w;
            sq[n]  += v.x * v.x + v.y * v.y + v.z * v.z + v.w * v.w;
        }
    }
    // prefetch layer_output (used only in phase 3)
    float4 lpre0 = lo4[tid];
    float4 lpre1 = lo4[tid + BLK];

    // wave shfl-xor tree (8 values)
    #pragma unroll
    for (int n = 0; n < NEXP; ++n) {
        #pragma unroll
        for (int off = 32; off > 0; off >>= 1) {
            sum[n] += __shfl_xor(sum[n], off, 64);
            sq[n]  += __shfl_xor(sq[n],  off, 64);
        }
    }
    if (lane == 0) {
        #pragma unroll
        for (int n = 0; n < NEXP; ++n) {
            red[wave][n]        = sum[n];
            red[wave][NEXP + n] = sq[n];
        }
    }
    __syncthreads();
    if (tid < NEXP) {
        float s = 0.f, s2 = 0.f;
        #pragma unroll
        for (int w = 0; w < NWAVE; ++w) { s += red[w][tid]; s2 += red[w][NEXP + tid]; }
        float m   = s * (1.f / D);
        float var = s2 * (1.f / D) - m * m;
        stats[0][tid] = m;
        stats[1][tid] = rsqrtf(var + EPSV);
    }
    __syncthreads();
    float mu[NEXP], rs[NEXP];
    #pragma unroll
    for (int n = 0; n < NEXP; ++n) { mu[n] = stats[0][n]; rs[n] = stats[1][n]; }

    // ---- Phase 1.5: H_bar for own 8 elements, from registers -> LDS (f32) ----
    #pragma unroll
    for (int k = 0; k < 2; ++k) {
        int d4 = tid + BLK * k;
        float4 hb;
        hb.x = 0.25f * ((h[0][k].x - mu[0]) * rs[0] + (h[1][k].x - mu[1]) * rs[1] +
                        (h[2][k].x - mu[2]) * rs[2] + (h[3][k].x - mu[3]) * rs[3]);
        hb.y = 0.25f * ((h[0][k].y - mu[0]) * rs[0] + (h[1][k].y - mu[1]) * rs[1] +
                        (h[2][k].y - mu[2]) * rs[2] + (h[3][k].y - mu[3]) * rs[3]);
        hb.z = 0.25f * ((h[0][k].z - mu[0]) * rs[0] + (h[1][k].z - mu[1]) * rs[1] +
                        (h[2][k].z - mu[2]) * rs[2] + (h[3][k].z - mu[3]) * rs[3]);
        hb.w = 0.25f * ((h[0][k].w - mu[0]) * rs[0] + (h[1][k].w - mu[1]) * rs[1] +
                        (h[2][k].w - mu[2]) * rs[2] + (h[3][k].w - mu[3]) * rs[3]);
        ((float4*)hb_lds)[d4] = hb;
    }
    __syncthreads();

    // ---- Phase 2: wave w owns columns 6w..6w+5; scans full D ----
    float acc[6];
    #pragma unroll
    for (int c = 0; c < 6; ++c) acc[c] = 0.f;

    const int cbase = wave * 6;
    const float4* Wt4 = (const float4*)Wt;          // [24][512]

    #pragma unroll
    for (int p = 0; p < 8; ++p) {
        int d4 = p * 64 + lane;                     // lane-contiguous
        float4 hb = ((const float4*)hb_lds)[d4];
        #pragma unroll
        for (int c = 0; c < 6; ++c) {
            float4 w = Wt4[(cbase + c) * (D / 4) + d4];
            acc[c] += hb.x * w.x + hb.y * w.y + hb.z * w.z + hb.w * w.w;
        }
    }
    // wave-internal tree -> complete sums (no cross-wave reduce needed)
    #pragma unroll
    for (int c = 0; c < 6; ++c) {
        #pragma unroll
        for (int off = 32; off > 0; off >>= 1)
            acc[c] += __shfl_xor(acc[c], off, 64);
    }
    if (lane == 0) {
        #pragma unroll
        for (int c = 0; c < 6; ++c) coef[cbase + c] = acc[c];
    }
    __syncthreads();
    if (tid < 24) {
        float t = tanhf(coef[tid]);
        float c;
        if (tid < 4) {
            c = s_beta[tid] * t + Bm[tid];
        } else if (tid < 8) {
            int n = tid - 4;
            c = s_alpha[n * 4] * t + Am[n];
        } else {
            int ij = tid - 8;
            c = s_alpha[ij] * t + Ar[ij];
        }
        coef[tid] = c;
    }
    __syncthreads();

    float Bd[NEXP], Amd[NEXP], Ard[NEXP][NEXP];
    #pragma unroll
    for (int n = 0; n < NEXP; ++n) { Bd[n] = coef[n]; Amd[n] = coef[4 + n]; }
    #pragma unroll
    for (int i = 0; i < NEXP; ++i)
        #pragma unroll
        for (int j = 0; j < NEXP; ++j) Ard[i][j] = coef[8 + i * 4 + j];

    // ---- Phase 3: outputs straight from registers ----
    #pragma unroll
    for (int k = 0; k < 2; ++k) {
        int d4 = tid + BLK * k;
        float4 l = (k == 0) ? lpre0 : lpre1;

        float4 mx = {0.f, 0.f, 0.f, 0.f};
        #pragma unroll
        for (int n = 0; n < NEXP; ++n) {
            mx.x += Amd[n] * h[n][k].x; mx.y += Amd[n] * h[n][k].y;
            mx.z += Amd[n] * h[n][k].z; mx.w += Amd[n] * h[n][k].w;
        }
        #pragma unroll
        for (int i = 0; i < NEXP; ++i) {
            float4 o;
            o.x = Bd[i] * l.x + mx.x;
            o.y = Bd[i] * l.y + mx.y;
            o.z = Bd[i] * l.z + mx.z;
            o.w = Bd[i] * l.w + mx.w;
            #pragma unroll
            for (int j = 0; j < NEXP; ++j) {
                o.x += Ard[i][j] * h[j][k].x;
                o.y += Ard[i][j] * h[j][k].y;
                o.z += Ard[i][j] * h[j][k].z;
                o.w += Ard[i][j] * h[j][k].w;
            }
            out4[i * (D / 4) + d4] = o;
        }
    }
}

extern "C" void kernel_launch(void* const* d_in, const int* in_sizes, int n_in,
                              void* d_out, int out_size, void* d_ws, size_t ws_size,
                              hipStream_t stream) {
    const float* lo      = (const float*)d_in[0];
    const float* hs      = (const float*)d_in[1];
    const float* Bm      = (const float*)d_in[2];
    const float* Am      = (const float*)d_in[3];
    const float* Ar      = (const float*)d_in[4];
    const float* s_alpha = (const float*)d_in[5];
    const float* s_beta  = (const float*)d_in[6];
    const float* Wb      = (const float*)d_in[7];
    const float* Wm      = (const float*)d_in[8];
    const float* Wr      = (const float*)d_in[9];
    float* out = (float*)d_out;
    float* Wt  = (float*)d_ws;                     // 24*2048*4 = 196 608 B

    wt_kernel<<<192, 256, 0, stream>>>(Wb, Wm, Wr, Wt);

    const int tokens = in_sizes[0] / D;            // 8192
    hc_kernel<<<tokens, BLK, 0, stream>>>(lo, hs, Bm, Am, Ar, s_alpha, s_beta,
                                          Wt, out);
}